// Round 4
// baseline (5362.400 us; speedup 1.0000x reference)
//
#include <hip/hip_runtime.h>
#include <stdint.h>

#define NQ 8192
#define NS 16384
#define DIM 512
#define NC 64
#define MARGIN 0.01f
#define CAND_CAP (1 << 20)   // 1M candidates (16 MB); expected ~400K

typedef unsigned short ushort;
typedef __attribute__((ext_vector_type(8))) short bf16x8;
typedef __attribute__((ext_vector_type(4))) float f32x4;

// ---------- helpers ----------
__device__ __forceinline__ uint32_t fkey(float f) {
  uint32_t u = __float_as_uint(f);
  return (u & 0x80000000u) ? ~u : (u | 0x80000000u);
}
__device__ __forceinline__ float unfkey(uint32_t k) {
  return __uint_as_float((k & 0x80000000u) ? (k & 0x7FFFFFFFu) : ~k);
}
__device__ __forceinline__ ushort f2bf_rne(float f) {
  uint32_t u = __float_as_uint(f);
  return (ushort)((u + 0x7fffu + ((u >> 16) & 1u)) >> 16);
}
__device__ __forceinline__ void gload_lds16(const void* g, void* lds) {
  __builtin_amdgcn_global_load_lds(
      (const __attribute__((address_space(1))) uint32_t*)g,
      (__attribute__((address_space(3))) uint32_t*)lds, 16, 0, 0);
}

// ---------- pre-pass: row-normalize -> bf16 + rnorm scale ----------
__global__ void norm_bf16_kernel(const float* __restrict__ X,
                                 ushort* __restrict__ Xbf, float* __restrict__ rX,
                                 int nrows) {
  int w = threadIdx.x >> 6, l = threadIdx.x & 63;
  int row = blockIdx.x * 4 + w;
  if (row >= nrows) return;
  const float4* x = (const float4*)(X + (size_t)row * DIM);
  float4 v0 = x[l], v1 = x[l + 64];
  float s = v0.x*v0.x + v0.y*v0.y + v0.z*v0.z + v0.w*v0.w
          + v1.x*v1.x + v1.y*v1.y + v1.z*v1.z + v1.w*v1.w;
  #pragma unroll
  for (int off = 32; off; off >>= 1) s += __shfl_xor(s, off);
  float r = rsqrtf(fmaxf(s, 1e-12f));
  if (l == 0) rX[row] = r;
  size_t base = (size_t)row * DIM + 4 * l;
  *(ushort4*)&Xbf[base] = make_ushort4(f2bf_rne(v0.x*r), f2bf_rne(v0.y*r),
                                       f2bf_rne(v0.z*r), f2bf_rne(v0.w*r));
  *(ushort4*)&Xbf[base + 256] = make_ushort4(f2bf_rne(v1.x*r), f2bf_rne(v1.y*r),
                                             f2bf_rne(v1.z*r), f2bf_rne(v1.w*r));
}

// labels from one-hot + zero result/candidate state (must re-init every call)
__global__ void label_init_kernel(const float* __restrict__ oh, int* __restrict__ lab,
                                  unsigned long long* __restrict__ packedE,
                                  uint32_t* __restrict__ packedA, int* __restrict__ cnt) {
  int i = blockIdx.x * 256 + threadIdx.x;
  if (i == 0) *cnt = 0;
  if (i < NQ) { packedE[i] = 0ull; packedA[i] = 0u; }
  if (i < NS) {
    const float* row = oh + (size_t)i * NC;
    int l = 0;
    #pragma unroll
    for (int j = 0; j < NC; ++j) l = (row[j] > 0.5f) ? j : l;
    lab[i] = l;
  }
}

// ---------- pass 1: bf16 GEMM, per-query chunk max + candidate emission ----------
__global__ __launch_bounds__(512, 2) void gemm_margin_kernel(
    const ushort* __restrict__ Qbf, const ushort* __restrict__ Sbf,
    uint32_t* __restrict__ packedA, int4* __restrict__ cand, int* __restrict__ cnt)
{
  // [buf][A/B][256 rows x 64 k] bf16, 128 B rows; XOR-swizzled slots. 128 KB.
  __shared__ ushort tiles[2][2][256 * 64];
  __shared__ float merged[256][4];
  __shared__ float runmax[256];

  const int tid = threadIdx.x;
  const int w = tid >> 6, l = tid & 63;
  const int wr = w >> 2, wcn = w & 3;           // 2 (M) x 4 (N) wave grid
  const int c = l & 15, g = l >> 4;

  // T1: XCD swizzle (512 blocks, bijective). Each XCD owns 2 s-chunks.
  const int flat = blockIdx.x;
  const int nf = (flat & 7) * 64 + (flat >> 3);
  const int sbq = nf >> 5, qb = nf & 31;
  const int qbase = qb * 256, sbase = sbq * 1024;

  // staging: per instr 8 rows x 128 B; lane -> row +(l>>3), phys slot l&7.
  // phys slot p at row r holds logical slot p ^ (r&7); rb%8==0 so src slot = (l&7)^(l>>3).
  const int lrow = l >> 3;
  const size_t lslot = (size_t)(((l & 7) ^ lrow) * 16);   // bytes
  const char* srcA[4]; const char* srcB[4]; int ldst[4];
  #pragma unroll
  for (int u = 0; u < 4; ++u) {
    int rb = w * 32 + u * 8;
    srcA[u] = (const char*)Qbf + (size_t)(qbase + rb + lrow) * (DIM * 2) + lslot;
    srcB[u] = (const char*)Sbf + (size_t)(sbase + rb + lrow) * (DIM * 2) + lslot;
    ldst[u] = rb * 128;   // wave-uniform byte offset in tile
  }

  #define STAGE_A(buf, ks1) do { int kb_ = ((ks1) & 7) * 128;                       \
    gload_lds16(srcA[0] + kb_, (char*)&tiles[(buf)][0][0] + ldst[0]);               \
    gload_lds16(srcA[1] + kb_, (char*)&tiles[(buf)][0][0] + ldst[1]);               \
    gload_lds16(srcA[2] + kb_, (char*)&tiles[(buf)][0][0] + ldst[2]);               \
    gload_lds16(srcA[3] + kb_, (char*)&tiles[(buf)][0][0] + ldst[3]);               \
  } while (0)
  #define STAGE_B(buf, ks1) do {                                                    \
    size_t off_ = (size_t)((ks1) >> 3) * 256 * (DIM * 2) + ((ks1) & 7) * 128;       \
    gload_lds16(srcB[0] + off_, (char*)&tiles[(buf)][1][0] + ldst[0]);              \
    gload_lds16(srcB[1] + off_, (char*)&tiles[(buf)][1][0] + ldst[1]);              \
    gload_lds16(srcB[2] + off_, (char*)&tiles[(buf)][1][0] + ldst[2]);              \
    gload_lds16(srcB[3] + off_, (char*)&tiles[(buf)][1][0] + ldst[3]);              \
  } while (0)

  // fragment read bases (bytes): row*128 + ((ks2*4+g)^(c&7))*16
  const int arow = (wr * 128 + c) * 128;
  const int brow = (wcn * 64 + c) * 128;
  const int sl0 = ((g) ^ (c & 7)) * 16;
  const int sl1 = ((4 + g) ^ (c & 7)) * 16;

  float rm = -2.0f;   // running chunk max for query row tid (tid<256)

  // prologue
  STAGE_A(0, 0); STAGE_B(0, 0);
  asm volatile("s_waitcnt vmcnt(0)" ::: "memory");
  __builtin_amdgcn_s_barrier();

  for (int t = 0; t < 4; ++t) {
    f32x4 acc[8][4];
    #pragma unroll
    for (int m = 0; m < 8; ++m)
      #pragma unroll
      for (int n = 0; n < 4; ++n) acc[m][n] = (f32x4)0.0f;

    for (int k8 = 0; k8 < 8; ++k8) {
      const int ks = t * 8 + k8;
      const int cur = ks & 1, nxt = cur ^ 1;
      const bool pf = (ks + 1 < 32);
      const char* At = (const char*)&tiles[cur][0][0];
      const char* Bt = (const char*)&tiles[cur][1][0];
      bf16x8 ah[8], bh[4];

      // ---- P1: k-slice 0 ----
      #pragma unroll
      for (int m = 0; m < 8; ++m) ah[m] = *(const bf16x8*)(At + arow + m * 16 * 128 + sl0);
      #pragma unroll
      for (int n = 0; n < 4; ++n) bh[n] = *(const bf16x8*)(Bt + brow + n * 16 * 128 + sl0);
      if (pf) STAGE_A(nxt, ks + 1);
      asm volatile("s_waitcnt lgkmcnt(0)" ::: "memory");
      __builtin_amdgcn_s_setprio(1);
      #pragma unroll
      for (int m = 0; m < 8; ++m)
        #pragma unroll
        for (int n = 0; n < 4; ++n)
          acc[m][n] = __builtin_amdgcn_mfma_f32_16x16x32_bf16(ah[m], bh[n], acc[m][n], 0, 0, 0);
      __builtin_amdgcn_s_setprio(0);

      // ---- P2: k-slice 1 ----
      #pragma unroll
      for (int m = 0; m < 8; ++m) ah[m] = *(const bf16x8*)(At + arow + m * 16 * 128 + sl1);
      #pragma unroll
      for (int n = 0; n < 4; ++n) bh[n] = *(const bf16x8*)(Bt + brow + n * 16 * 128 + sl1);
      if (pf) STAGE_B(nxt, ks + 1);
      asm volatile("s_waitcnt lgkmcnt(0)" ::: "memory");
      __builtin_amdgcn_s_setprio(1);
      #pragma unroll
      for (int m = 0; m < 8; ++m)
        #pragma unroll
        for (int n = 0; n < 4; ++n)
          acc[m][n] = __builtin_amdgcn_mfma_f32_16x16x32_bf16(ah[m], bh[n], acc[m][n], 0, 0, 0);
      __builtin_amdgcn_s_setprio(0);

      asm volatile("s_waitcnt vmcnt(0)" ::: "memory");  // own prefetch landed
      __builtin_amdgcn_s_barrier();                     // everyone's tile ready
    }

    // ---- epilogue: rowmax merge + runmax + candidate emission ----
    // C/D: col = wcn*64 + j*16 + c ; row = wr*128 + m*16 + g*4 + r
    #pragma unroll
    for (int m = 0; m < 8; ++m)
      #pragma unroll
      for (int r = 0; r < 4; ++r) {
        float v = acc[m][0][r];
        #pragma unroll
        for (int j = 1; j < 4; ++j) v = fmaxf(v, acc[m][j][r]);
        #pragma unroll
        for (int off = 1; off < 16; off <<= 1) v = fmaxf(v, __shfl_xor(v, off));
        if (c == 0) merged[wr * 128 + m * 16 + g * 4 + r][wcn] = v;
      }
    __syncthreads();
    if (tid < 256) {
      float tmax = fmaxf(fmaxf(merged[tid][0], merged[tid][1]),
                         fmaxf(merged[tid][2], merged[tid][3]));
      rm = fmaxf(rm, tmax);
      runmax[tid] = rm;
    }
    __syncthreads();
    {
      const int sb = sbase + t * 256 + wcn * 64 + c;
      #pragma unroll
      for (int m = 0; m < 8; ++m)
        #pragma unroll
        for (int r = 0; r < 4; ++r) {
          int row = wr * 128 + m * 16 + g * 4 + r;
          float thr = runmax[row] - MARGIN;
          #pragma unroll
          for (int j = 0; j < 4; ++j) {
            float v = acc[m][j][r];
            if (v >= thr) {
              int idx = atomicAdd(cnt, 1);
              if (idx < CAND_CAP)
                cand[idx] = make_int4(qbase + row, sb + j * 16, __float_as_int(v), 0);
            }
          }
        }
    }
    __syncthreads();   // emission reads runmax before next tile overwrites it
  }

  if (tid < 256) atomicMax(&packedA[qbase + tid], fkey(rm));

  #undef STAGE_A
  #undef STAGE_B
}

// ---------- pass 2: exact fp32 rescore of filtered candidates ----------
__global__ void rescore_kernel(const float* __restrict__ Q, const float* __restrict__ S,
                               const float* __restrict__ rq, const float* __restrict__ rs,
                               const uint32_t* __restrict__ packedA,
                               const int4* __restrict__ cand, const int* __restrict__ cnt,
                               unsigned long long* __restrict__ packedE) {
  const int nw = (gridDim.x * blockDim.x) >> 6;
  const int wid = (blockIdx.x * blockDim.x + threadIdx.x) >> 6;
  const int l = threadIdx.x & 63;
  int n = *cnt; if (n > CAND_CAP) n = CAND_CAP;
  for (int ci = wid; ci < n; ci += nw) {
    int4 cd = cand[ci];
    float maxA = unfkey(packedA[cd.x]);
    float apx = __int_as_float(cd.z);
    if (apx < maxA - MARGIN) continue;     // can't be the winner
    const float4* qp = (const float4*)(Q + (size_t)cd.x * DIM);
    const float4* sp = (const float4*)(S + (size_t)cd.y * DIM);
    float4 a0 = qp[l], b0 = sp[l], a1 = qp[l + 64], b1 = sp[l + 64];
    float d = a0.x*b0.x + a0.y*b0.y + a0.z*b0.z + a0.w*b0.w
            + a1.x*b1.x + a1.y*b1.y + a1.z*b1.z + a1.w*b1.w;
    #pragma unroll
    for (int off = 32; off; off >>= 1) d += __shfl_xor(d, off);
    if (l == 0) {
      float ex = d * rq[cd.x] * rs[cd.y];
      unsigned long long p =
          ((unsigned long long)fkey(ex) << 32) | (uint32_t)(~(uint32_t)cd.y);
      atomicMax(&packedE[cd.x], p);
    }
  }
}

__global__ void finalize_kernel(const unsigned long long* __restrict__ packedE,
                                const int* __restrict__ lab, float* __restrict__ out) {
  int gid = blockIdx.x * 256 + threadIdx.x;
  if (gid >= NQ * NC) return;
  int q = gid >> 6, cl = gid & 63;
  unsigned long long p = packedE[q];
  if (p == 0ull) { out[gid] = 0.0f; return; }   // safety: never expected
  uint32_t n = ~(uint32_t)p;
  float v = unfkey((uint32_t)(p >> 32));
  out[gid] = (cl == lab[n]) ? v : 0.0f;
}

// ---------- launch ----------
extern "C" void kernel_launch(void* const* d_in, const int* in_sizes, int n_in,
                              void* d_out, int out_size, void* d_ws, size_t ws_size,
                              hipStream_t stream) {
  const float* Q  = (const float*)d_in[0];   // [8192, 512]
  const float* S  = (const float*)d_in[1];   // [16384, 512]
  const float* OH = (const float*)d_in[2];   // [16384, 64]
  float* out = (float*)d_out;                // [8192, 64]

  char* ws = (char*)d_ws;
  int* lab                    = (int*)(ws);                      //  64 KB
  unsigned long long* packedE = (unsigned long long*)(ws + (1 << 16));  // 64 KB
  uint32_t* packedA           = (uint32_t*)(ws + (2 << 16));     //  32 KB
  int* cnt                    = (int*)(ws + (3 << 16));          //   4 KB
  float* rq                   = (float*)(ws + 200704);           //  32 KB
  float* rs                   = (float*)(ws + 233472);           //  64 KB
  ushort* Qbf                 = (ushort*)(ws + 299008);          //   8 MB
  ushort* Sbf                 = (ushort*)(ws + 299008 + 8388608);        // 16 MB
  int4* cand                  = (int4*)(ws + 299008 + 8388608 + 16777216); // 16 MB

  norm_bf16_kernel<<<NQ / 4, 256, 0, stream>>>(Q, Qbf, rq, NQ);
  norm_bf16_kernel<<<NS / 4, 256, 0, stream>>>(S, Sbf, rs, NS);
  label_init_kernel<<<NS / 256, 256, 0, stream>>>(OH, lab, packedE, packedA, cnt);

  gemm_margin_kernel<<<512, 512, 0, stream>>>(Qbf, Sbf, packedA, cand, cnt);

  rescore_kernel<<<2048, 256, 0, stream>>>(Q, S, rq, rs, packedA, cand, cnt, packedE);

  finalize_kernel<<<(NQ * NC) / 256, 256, 0, stream>>>(packedE, lab, out);
}

// Round 5
// 302.048 us; speedup vs baseline: 17.7535x; 17.7535x over previous
//
#include <hip/hip_runtime.h>
#include <stdint.h>

#define NQ 8192
#define NS 16384
#define DIM 512
#define NC 64
#define MARGIN 0.01f
#define CAND_CAP (1 << 20)     // 1M global candidates (16 MB)
#define LCAP 1024              // per-block-tile LDS candidate cap

typedef unsigned short ushort;
typedef __attribute__((ext_vector_type(8))) short bf16x8;
typedef __attribute__((ext_vector_type(4))) float f32x4;

// ---------- helpers ----------
__device__ __forceinline__ uint32_t fkey(float f) {
  uint32_t u = __float_as_uint(f);
  return (u & 0x80000000u) ? ~u : (u | 0x80000000u);
}
__device__ __forceinline__ float unfkey(uint32_t k) {
  return __uint_as_float((k & 0x80000000u) ? (k & 0x7FFFFFFFu) : ~k);
}
__device__ __forceinline__ ushort f2bf_rne(float f) {
  uint32_t u = __float_as_uint(f);
  return (ushort)((u + 0x7fffu + ((u >> 16) & 1u)) >> 16);
}
__device__ __forceinline__ void gload_lds16(const void* g, void* lds) {
  __builtin_amdgcn_global_load_lds(
      (const __attribute__((address_space(1))) uint32_t*)g,
      (__attribute__((address_space(3))) uint32_t*)lds, 16, 0, 0);
}

// ---------- pre-pass: row-normalize -> bf16 + rnorm scale ----------
__global__ void norm_bf16_kernel(const float* __restrict__ X,
                                 ushort* __restrict__ Xbf, float* __restrict__ rX,
                                 int nrows) {
  int w = threadIdx.x >> 6, l = threadIdx.x & 63;
  int row = blockIdx.x * 4 + w;
  if (row >= nrows) return;
  const float4* x = (const float4*)(X + (size_t)row * DIM);
  float4 v0 = x[l], v1 = x[l + 64];
  float s = v0.x*v0.x + v0.y*v0.y + v0.z*v0.z + v0.w*v0.w
          + v1.x*v1.x + v1.y*v1.y + v1.z*v1.z + v1.w*v1.w;
  #pragma unroll
  for (int off = 32; off; off >>= 1) s += __shfl_xor(s, off);
  float r = rsqrtf(fmaxf(s, 1e-12f));
  if (l == 0) rX[row] = r;
  size_t base = (size_t)row * DIM + 4 * l;
  *(ushort4*)&Xbf[base] = make_ushort4(f2bf_rne(v0.x*r), f2bf_rne(v0.y*r),
                                       f2bf_rne(v0.z*r), f2bf_rne(v0.w*r));
  *(ushort4*)&Xbf[base + 256] = make_ushort4(f2bf_rne(v1.x*r), f2bf_rne(v1.y*r),
                                             f2bf_rne(v1.z*r), f2bf_rne(v1.w*r));
}

// labels from one-hot + zero result/candidate state (must re-init every call)
__global__ void label_init_kernel(const float* __restrict__ oh, int* __restrict__ lab,
                                  unsigned long long* __restrict__ packedE,
                                  uint32_t* __restrict__ packedA, int* __restrict__ cnt) {
  int i = blockIdx.x * 256 + threadIdx.x;
  if (i == 0) *cnt = 0;
  if (i < NQ) { packedE[i] = 0ull; packedA[i] = 0u; }
  if (i < NS) {
    const float* row = oh + (size_t)i * NC;
    int l = 0;
    #pragma unroll
    for (int j = 0; j < NC; ++j) l = (row[j] > 0.5f) ? j : l;
    lab[i] = l;
  }
}

// ---------- pass 1: bf16 GEMM (128x256 tile), chunk max + candidate emission ----------
__global__ __launch_bounds__(512, 2) void gemm_margin_kernel(
    const ushort* __restrict__ Qbf, const ushort* __restrict__ Sbf,
    uint32_t* __restrict__ packedA, int4* __restrict__ cand, int* __restrict__ cnt)
{
  // A: 128 rows x 64 k (16 KB), B: 256 rows x 64 k (32 KB); double-buffered = 96 KB.
  // 128 B rows; phys 16B-slot p holds logical slot p ^ (row & 7)  [round-4 verified: 0 conflicts]
  __shared__ ushort Atile[2][128 * 64];
  __shared__ ushort Btile[2][256 * 64];
  __shared__ float merged[128][4];
  __shared__ float runmax[128];
  __shared__ int4 lbuf[LCAP];           // 16 KB
  __shared__ int lcnt, lbase;

  const int tid = threadIdx.x;
  const int w = tid >> 6, l = tid & 63;
  const int wr = w >> 2, wcn = w & 3;           // 2 (M) x 4 (N) wave grid
  const int c = l & 15, g = l >> 4;

  // T1: XCD swizzle (1024 blocks, 1024 % 8 == 0, bijective)
  const int flat = blockIdx.x;
  const int nf = (flat & 7) * 128 + (flat >> 3);
  const int sbq = nf >> 6, qb = nf & 63;        // 16 s-chunks x 64 q-blocks
  const int qbase = qb * 128, sbase = sbq * 1024;

  // staging: per instr one wave covers 8 rows x 128 B (8 lanes/row, 16 B each)
  const int lrow = l >> 3;
  const size_t lslot = (size_t)(((l & 7) ^ lrow) * 16);   // pre-swizzled src slot (bytes)
  const char* srcA = (const char*)Qbf + (size_t)(qbase + w * 8 + lrow) * 1024 + lslot;
  const char* srcB = (const char*)Sbf + (size_t)(sbase + w * 8 + lrow) * 1024 + lslot;
  const int ldst = (w * 8) * 128;               // wave-uniform byte offset

  #define STAGE_A(buf, ks1) do { const size_t kb_ = (size_t)(((ks1) & 7) * 128);       \
    gload_lds16(srcA + kb_,             (char*)&Atile[(buf)][0] + ldst);               \
    gload_lds16(srcA + kb_ + 64 * 1024, (char*)&Atile[(buf)][0] + ldst + 64 * 128);    \
  } while (0)
  #define STAGE_B(buf, ks1) do {                                                       \
    const size_t ob_ = (size_t)((ks1) >> 3) * 256 * 1024 + (size_t)(((ks1) & 7) * 128);\
    gload_lds16(srcB + ob_,              (char*)&Btile[(buf)][0] + ldst);              \
    gload_lds16(srcB + ob_ +  64 * 1024, (char*)&Btile[(buf)][0] + ldst +  64 * 128);  \
    gload_lds16(srcB + ob_ + 128 * 1024, (char*)&Btile[(buf)][0] + ldst + 128 * 128);  \
    gload_lds16(srcB + ob_ + 192 * 1024, (char*)&Btile[(buf)][0] + ldst + 192 * 128);  \
  } while (0)

  // fragment read bases (bytes)
  const int arow = (wr * 64 + c) * 128;
  const int brow = (wcn * 64 + c) * 128;
  const int sl0 = (g ^ (c & 7)) * 16;           // k-slices 0-3
  const int sl1 = ((4 + g) ^ (c & 7)) * 16;     // k-slices 4-7

  float rm = -2.0f;                              // running chunk max (tid < 128)
  if (tid == 0) lcnt = 0;

  // prologue: stage K-step 0 into buf 0
  STAGE_A(0, 0); STAGE_B(0, 0);
  asm volatile("s_waitcnt vmcnt(0)" ::: "memory");
  __builtin_amdgcn_s_barrier();

  for (int t = 0; t < 4; ++t) {
    f32x4 acc[4][4];
    #pragma unroll
    for (int m = 0; m < 4; ++m)
      #pragma unroll
      for (int n = 0; n < 4; ++n) acc[m][n] = (f32x4)0.0f;

    for (int k8 = 0; k8 < 8; ++k8) {
      const int ks = t * 8 + k8;
      const int cur = ks & 1, nxt = cur ^ 1;
      const bool pf = (ks + 1 < 32);
      const char* At = (const char*)&Atile[cur][0];
      const char* Bt = (const char*)&Btile[cur][0];
      bf16x8 ah[4], bh[4];

      // ---- P1: k-slices 0-3 ----
      #pragma unroll
      for (int m = 0; m < 4; ++m) ah[m] = *(const bf16x8*)(At + arow + m * 16 * 128 + sl0);
      #pragma unroll
      for (int n = 0; n < 4; ++n) bh[n] = *(const bf16x8*)(Bt + brow + n * 16 * 128 + sl0);
      if (pf) STAGE_A(nxt, ks + 1);
      asm volatile("s_waitcnt lgkmcnt(0)" ::: "memory");
      __builtin_amdgcn_s_setprio(1);
      #pragma unroll
      for (int m = 0; m < 4; ++m)
        #pragma unroll
        for (int n = 0; n < 4; ++n)
          acc[m][n] = __builtin_amdgcn_mfma_f32_16x16x32_bf16(ah[m], bh[n], acc[m][n], 0, 0, 0);
      __builtin_amdgcn_s_setprio(0);

      // ---- P2: k-slices 4-7 ----
      #pragma unroll
      for (int m = 0; m < 4; ++m) ah[m] = *(const bf16x8*)(At + arow + m * 16 * 128 + sl1);
      #pragma unroll
      for (int n = 0; n < 4; ++n) bh[n] = *(const bf16x8*)(Bt + brow + n * 16 * 128 + sl1);
      if (pf) STAGE_B(nxt, ks + 1);
      asm volatile("s_waitcnt lgkmcnt(0)" ::: "memory");
      __builtin_amdgcn_s_setprio(1);
      #pragma unroll
      for (int m = 0; m < 4; ++m)
        #pragma unroll
        for (int n = 0; n < 4; ++n)
          acc[m][n] = __builtin_amdgcn_mfma_f32_16x16x32_bf16(ah[m], bh[n], acc[m][n], 0, 0, 0);
      __builtin_amdgcn_s_setprio(0);

      asm volatile("s_waitcnt vmcnt(0)" ::: "memory");  // own prefetch landed
      __builtin_amdgcn_s_barrier();                     // everyone's tile ready
    }

    // ---- epilogue: rowmax merge -> runmax -> two-level candidate emission ----
    // C/D: col = wcn*64 + j*16 + c ; row = wr*64 + m*16 + g*4 + r
    #pragma unroll
    for (int m = 0; m < 4; ++m)
      #pragma unroll
      for (int r = 0; r < 4; ++r) {
        float v = acc[m][0][r];
        #pragma unroll
        for (int j = 1; j < 4; ++j) v = fmaxf(v, acc[m][j][r]);
        #pragma unroll
        for (int off = 1; off < 16; off <<= 1) v = fmaxf(v, __shfl_xor(v, off));
        if (c == 0) merged[wr * 64 + m * 16 + g * 4 + r][wcn] = v;
      }
    __syncthreads();
    if (tid < 128) {
      float tmax = fmaxf(fmaxf(merged[tid][0], merged[tid][1]),
                         fmaxf(merged[tid][2], merged[tid][3]));
      rm = fmaxf(rm, tmax);
      runmax[tid] = rm;
    }
    __syncthreads();
    {
      const int sb = sbase + t * 256 + wcn * 64 + c;
      #pragma unroll
      for (int m = 0; m < 4; ++m)
        #pragma unroll
        for (int r = 0; r < 4; ++r) {
          const int row = wr * 64 + m * 16 + g * 4 + r;
          const float thr = runmax[row] - MARGIN;
          #pragma unroll
          for (int j = 0; j < 4; ++j) {
            float v = acc[m][j][r];
            if (v >= thr) {
              int s = atomicAdd(&lcnt, 1);     // LDS atomic: block-local
              if (s < LCAP)
                lbuf[s] = make_int4(qbase + row, sb + j * 16, __float_as_int(v), 0);
            }
          }
        }
    }
    __syncthreads();
    if (tid == 0) {                             // ONE global atomic per block-tile
      int take = lcnt < LCAP ? lcnt : LCAP;
      lbase = atomicAdd(cnt, take);
      lcnt = take;                              // clamp for the copy loop
    }
    __syncthreads();
    for (int i = tid; i < lcnt; i += 512) {
      int gi = lbase + i;
      if (gi < CAND_CAP) cand[gi] = lbuf[i];
    }
    __syncthreads();
    if (tid == 0) lcnt = 0;
    // next K-loop's barriers order this reset before the next tile's emission
  }

  if (tid < 128) atomicMax(&packedA[qbase + tid], fkey(rm));

  #undef STAGE_A
  #undef STAGE_B
}

// ---------- pass 2: exact fp32 rescore of filtered candidates ----------
__global__ void rescore_kernel(const float* __restrict__ Q, const float* __restrict__ S,
                               const float* __restrict__ rq, const float* __restrict__ rs,
                               const uint32_t* __restrict__ packedA,
                               const int4* __restrict__ cand, const int* __restrict__ cnt,
                               unsigned long long* __restrict__ packedE) {
  const int nw = (gridDim.x * blockDim.x) >> 6;
  const int wid = (blockIdx.x * blockDim.x + threadIdx.x) >> 6;
  const int l = threadIdx.x & 63;
  int n = *cnt; if (n > CAND_CAP) n = CAND_CAP;
  for (int ci = wid; ci < n; ci += nw) {
    int4 cd = cand[ci];
    float maxA = unfkey(packedA[cd.x]);
    float apx = __int_as_float(cd.z);
    if (apx < maxA - MARGIN) continue;     // provably not the winner
    const float4* qp = (const float4*)(Q + (size_t)cd.x * DIM);
    const float4* sp = (const float4*)(S + (size_t)cd.y * DIM);
    float4 a0 = qp[l], b0 = sp[l], a1 = qp[l + 64], b1 = sp[l + 64];
    float d = a0.x*b0.x + a0.y*b0.y + a0.z*b0.z + a0.w*b0.w
            + a1.x*b1.x + a1.y*b1.y + a1.z*b1.z + a1.w*b1.w;
    #pragma unroll
    for (int off = 32; off; off >>= 1) d += __shfl_xor(d, off);
    if (l == 0) {
      float ex = d * rq[cd.x] * rs[cd.y];
      unsigned long long p =
          ((unsigned long long)fkey(ex) << 32) | (uint32_t)(~(uint32_t)cd.y);
      atomicMax(&packedE[cd.x], p);
    }
  }
}

__global__ void finalize_kernel(const unsigned long long* __restrict__ packedE,
                                const int* __restrict__ lab, float* __restrict__ out) {
  int gid = blockIdx.x * 256 + threadIdx.x;
  if (gid >= NQ * NC) return;
  int q = gid >> 6, cl = gid & 63;
  unsigned long long p = packedE[q];
  if (p == 0ull) { out[gid] = 0.0f; return; }   // safety: never expected
  uint32_t n = ~(uint32_t)p;
  float v = unfkey((uint32_t)(p >> 32));
  out[gid] = (cl == lab[n]) ? v : 0.0f;
}

// ---------- launch ----------
extern "C" void kernel_launch(void* const* d_in, const int* in_sizes, int n_in,
                              void* d_out, int out_size, void* d_ws, size_t ws_size,
                              hipStream_t stream) {
  const float* Q  = (const float*)d_in[0];   // [8192, 512]
  const float* S  = (const float*)d_in[1];   // [16384, 512]
  const float* OH = (const float*)d_in[2];   // [16384, 64]
  float* out = (float*)d_out;                // [8192, 64]

  char* ws = (char*)d_ws;
  int* lab                    = (int*)(ws);                             //  64 KB
  unsigned long long* packedE = (unsigned long long*)(ws + (1 << 16));  //  64 KB
  uint32_t* packedA           = (uint32_t*)(ws + (2 << 16));            //  32 KB
  int* cnt                    = (int*)(ws + (3 << 16));                 //   4 KB
  float* rq                   = (float*)(ws + 200704);                  //  32 KB
  float* rs                   = (float*)(ws + 233472);                  //  64 KB
  ushort* Qbf                 = (ushort*)(ws + 299008);                 //   8 MB
  ushort* Sbf                 = (ushort*)(ws + 299008 + 8388608);       //  16 MB
  int4* cand                  = (int4*)(ws + 299008 + 8388608 + 16777216); // 16 MB

  norm_bf16_kernel<<<NQ / 4, 256, 0, stream>>>(Q, Qbf, rq, NQ);
  norm_bf16_kernel<<<NS / 4, 256, 0, stream>>>(S, Sbf, rs, NS);
  label_init_kernel<<<NS / 256, 256, 0, stream>>>(OH, lab, packedE, packedA, cnt);

  gemm_margin_kernel<<<1024, 512, 0, stream>>>(Qbf, Sbf, packedA, cand, cnt);

  rescore_kernel<<<2048, 256, 0, stream>>>(Q, S, rq, rs, packedA, cand, cnt, packedE);

  finalize_kernel<<<(NQ * NC) / 256, 256, 0, stream>>>(packedE, lab, out);
}

// Round 6
// 290.314 us; speedup vs baseline: 18.4710x; 1.0404x over previous
//
#include <hip/hip_runtime.h>
#include <stdint.h>

#define NQ 8192
#define NS 16384
#define DIM 512
#define NC 64
#define MARGIN 0.01f
#define CAND_CAP (1 << 20)     // 1M global candidates (16 MB)
#define LCAP 2048              // per-block-tile LDS candidate cap

#define BM 256
#define BN 256
#define BK 32
#define SSPLIT 8
#define SCHUNK (NS / SSPLIT)   // 2048
#define NTILES (SCHUNK / BN)   // 8
#define KSTEPS (DIM / BK)      // 16
#define TOTKS (NTILES * KSTEPS) // 128 linear K-steps per block

typedef unsigned short ushort;
typedef __attribute__((ext_vector_type(8))) short bf16x8;
typedef __attribute__((ext_vector_type(4))) float f32x4;

// ---------- helpers ----------
__device__ __forceinline__ uint32_t fkey(float f) {
  uint32_t u = __float_as_uint(f);
  return (u & 0x80000000u) ? ~u : (u | 0x80000000u);
}
__device__ __forceinline__ float unfkey(uint32_t k) {
  return __uint_as_float((k & 0x80000000u) ? (k & 0x7FFFFFFFu) : ~k);
}
__device__ __forceinline__ ushort f2bf_rne(float f) {
  uint32_t u = __float_as_uint(f);
  return (ushort)((u + 0x7fffu + ((u >> 16) & 1u)) >> 16);
}
__device__ __forceinline__ void gload_lds16(const void* g, void* lds) {
  __builtin_amdgcn_global_load_lds(
      (const __attribute__((address_space(1))) uint32_t*)g,
      (__attribute__((address_space(3))) uint32_t*)lds, 16, 0, 0);
}

// ---------- pre-pass: row-normalize -> bf16 + rnorm scale ----------
__global__ void norm_bf16_kernel(const float* __restrict__ X,
                                 ushort* __restrict__ Xbf, float* __restrict__ rX,
                                 int nrows) {
  int w = threadIdx.x >> 6, l = threadIdx.x & 63;
  int row = blockIdx.x * 4 + w;
  if (row >= nrows) return;
  const float4* x = (const float4*)(X + (size_t)row * DIM);
  float4 v0 = x[l], v1 = x[l + 64];
  float s = v0.x*v0.x + v0.y*v0.y + v0.z*v0.z + v0.w*v0.w
          + v1.x*v1.x + v1.y*v1.y + v1.z*v1.z + v1.w*v1.w;
  #pragma unroll
  for (int off = 32; off; off >>= 1) s += __shfl_xor(s, off);
  float r = rsqrtf(fmaxf(s, 1e-12f));
  if (l == 0) rX[row] = r;
  size_t base = (size_t)row * DIM + 4 * l;
  *(ushort4*)&Xbf[base] = make_ushort4(f2bf_rne(v0.x*r), f2bf_rne(v0.y*r),
                                       f2bf_rne(v0.z*r), f2bf_rne(v0.w*r));
  *(ushort4*)&Xbf[base + 256] = make_ushort4(f2bf_rne(v1.x*r), f2bf_rne(v1.y*r),
                                             f2bf_rne(v1.z*r), f2bf_rne(v1.w*r));
}

// labels from one-hot + zero result/candidate state (must re-init every call)
__global__ void label_init_kernel(const float* __restrict__ oh, int* __restrict__ lab,
                                  unsigned long long* __restrict__ packedE,
                                  uint32_t* __restrict__ packedA, int* __restrict__ cnt) {
  int i = blockIdx.x * 256 + threadIdx.x;
  if (i == 0) *cnt = 0;
  if (i < NQ) { packedE[i] = 0ull; packedA[i] = 0u; }
  if (i < NS) {
    const float* row = oh + (size_t)i * NC;
    int l = 0;
    #pragma unroll
    for (int j = 0; j < NC; ++j) l = (row[j] > 0.5f) ? j : l;
    lab[i] = l;
  }
}

// ---------- pass 1: bf16 GEMM (256x256, ring-of-3, counted vmcnt) ----------
__global__ __launch_bounds__(512, 1) void gemm_margin_kernel(
    const ushort* __restrict__ Qbf, const ushort* __restrict__ Sbf,
    uint32_t* __restrict__ packedA, int4* __restrict__ cand, int* __restrict__ cnt)
{
  // ring of 3: [buf][A/B][256 rows x 32 k] bf16, 64 B rows = 96 KB.
  // phys 16B-granule p at row r holds logical granule p ^ (r & 3)   (bank-uniform)
  __shared__ ushort tiles[3][2][BM * BK];
  __shared__ float merged[BM][4];
  __shared__ float runmax[BM];
  __shared__ int4 lbuf[LCAP];           // 32 KB
  __shared__ int lcnt, lbase;

  const int tid = threadIdx.x;
  const int w = tid >> 6, l = tid & 63;
  const int wr = w >> 2, wcn = w & 3;           // 2 (M) x 4 (N) wave grid
  const int c = l & 15, g = l >> 4;

  // T1: XCD swizzle (256 blocks, bijective). Each XCD = 1 s-chunk x 32 q-panels.
  const int flat = blockIdx.x;
  const int nf = (flat & 7) * 32 + (flat >> 3);
  const int sbq = nf >> 5, qb = nf & 31;
  const int qbase = qb * BM, sbase = sbq * SCHUNK;

  // staging: one gload16 per wave covers 16 rows x 64 B (4 lanes/row, 16 B each)
  const int lrow = l >> 2;                               // 0..15
  const int lslot = ((l & 3) ^ (lrow & 3)) * 16;         // pre-swizzled src granule
  const char* srcA0 = (const char*)Qbf + (size_t)(qbase + w * 32 + lrow) * 1024 + lslot;
  const char* srcB0 = (const char*)Sbf + (size_t)(sbase + w * 32 + lrow) * 1024 + lslot;
  const int ldst0 = (w * 32) * 64;                       // wave-uniform dest (bytes)

  // STAGE(n): 4 gload16/thread -> buf n%3. A k-block = (n&15)*64 B; B adds t-tile.
  #define STAGE(n) do {                                                         \
    const int nb_ = (n) % 3;                                                    \
    const int kb_ = ((n) & (KSTEPS - 1)) * 64;                                  \
    const size_t ob_ = (size_t)((n) >> 4) * (BN * 1024) + kb_;                  \
    char* at_ = (char*)&tiles[nb_][0][0];                                       \
    char* bt_ = (char*)&tiles[nb_][1][0];                                       \
    gload_lds16(srcA0 + kb_,         at_ + ldst0);                              \
    gload_lds16(srcA0 + kb_ + 16384, at_ + ldst0 + 1024);                       \
    gload_lds16(srcB0 + ob_,         bt_ + ldst0);                              \
    gload_lds16(srcB0 + ob_ + 16384, bt_ + ldst0 + 1024);                       \
  } while (0)

  // fragment read bases (bytes): row r, k-slice g -> r*64 + (g^(r&3))*16; r&3 == c&3
  const int slot = (g ^ (c & 3)) * 16;
  const int aoff = (wr * 128 + c) * 64 + slot;
  const int boff = (wcn * 64 + c) * 64 + slot;

  float rm = -2.0f;                              // running chunk max (tid < 256)
  if (tid == 0) lcnt = 0;

  // prologue: stage steps 0,1
  STAGE(0); STAGE(1);
  asm volatile("s_waitcnt vmcnt(4)" ::: "memory");   // step-0 loads landed
  __builtin_amdgcn_s_barrier();

  for (int t = 0; t < NTILES; ++t) {
    f32x4 acc[8][4];
    #pragma unroll
    for (int m = 0; m < 8; ++m)
      #pragma unroll
      for (int n = 0; n < 4; ++n) acc[m][n] = (f32x4)0.0f;

    for (int k16 = 0; k16 < KSTEPS; ++k16) {
      const int n = t * KSTEPS + k16;
      const int cur = n % 3;
      const char* At = (const char*)&tiles[cur][0][0];
      const char* Bt = (const char*)&tiles[cur][1][0];

      bf16x8 ah[8], bh[4];
      #pragma unroll
      for (int m = 0; m < 8; ++m) ah[m] = *(const bf16x8*)(At + aoff + m * 1024);
      #pragma unroll
      for (int j = 0; j < 4; ++j) bh[j] = *(const bf16x8*)(Bt + boff + j * 1024);

      if (n + 2 < TOTKS) STAGE(n + 2);

      __builtin_amdgcn_s_setprio(1);
      #pragma unroll
      for (int m = 0; m < 8; ++m)
        #pragma unroll
        for (int j = 0; j < 4; ++j)
          acc[m][j] = __builtin_amdgcn_mfma_f32_16x16x32_bf16(ah[m], bh[j], acc[m][j], 0, 0, 0);
      __builtin_amdgcn_s_setprio(0);

      // counted drain: stage(n+1) (4 older loads) done; stage(n+2) stays in flight
      asm volatile("s_waitcnt vmcnt(4)" ::: "memory");
      __builtin_amdgcn_s_barrier();
    }

    // ---- epilogue: rowmax merge -> runmax -> two-level candidate emission ----
    // C/D: col = wcn*64 + j*16 + c ; row = wr*128 + m*16 + g*4 + r
    #pragma unroll
    for (int m = 0; m < 8; ++m)
      #pragma unroll
      for (int r = 0; r < 4; ++r) {
        float v = acc[m][0][r];
        #pragma unroll
        for (int j = 1; j < 4; ++j) v = fmaxf(v, acc[m][j][r]);
        #pragma unroll
        for (int off = 1; off < 16; off <<= 1) v = fmaxf(v, __shfl_xor(v, off));
        if (c == 0) merged[wr * 128 + m * 16 + g * 4 + r][wcn] = v;
      }
    __syncthreads();
    if (tid < BM) {
      float tmax = fmaxf(fmaxf(merged[tid][0], merged[tid][1]),
                         fmaxf(merged[tid][2], merged[tid][3]));
      rm = fmaxf(rm, tmax);
      runmax[tid] = rm;
    }
    __syncthreads();
    {
      const int sb = sbase + t * BN + wcn * 64 + c;
      #pragma unroll
      for (int m = 0; m < 8; ++m)
        #pragma unroll
        for (int r = 0; r < 4; ++r) {
          const int row = wr * 128 + m * 16 + g * 4 + r;
          const float thr = runmax[row] - MARGIN;
          #pragma unroll
          for (int j = 0; j < 4; ++j) {
            float v = acc[m][j][r];
            if (v >= thr) {
              int s = atomicAdd(&lcnt, 1);     // LDS atomic: block-local
              if (s < LCAP)
                lbuf[s] = make_int4(qbase + row, sb + j * 16, __float_as_int(v), 0);
            }
          }
        }
    }
    __syncthreads();
    if (tid == 0) {                             // ONE global atomic per block-tile
      int take = lcnt < LCAP ? lcnt : LCAP;
      lbase = atomicAdd(cnt, take);
      lcnt = take;
    }
    __syncthreads();
    for (int i = tid; i < lcnt; i += 512) {
      int gi = lbase + i;
      if (gi < CAND_CAP) cand[gi] = lbuf[i];
    }
    __syncthreads();
    if (tid == 0) lcnt = 0;
    __syncthreads();   // reset visible before next tile's emission
  }

  if (tid < BM) atomicMax(&packedA[qbase + tid], fkey(rm));

  #undef STAGE
}

// ---------- pass 2: exact fp32 rescore of filtered candidates ----------
__global__ void rescore_kernel(const float* __restrict__ Q, const float* __restrict__ S,
                               const float* __restrict__ rq, const float* __restrict__ rs,
                               const uint32_t* __restrict__ packedA,
                               const int4* __restrict__ cand, const int* __restrict__ cnt,
                               unsigned long long* __restrict__ packedE) {
  const int nw = (gridDim.x * blockDim.x) >> 6;
  const int wid = (blockIdx.x * blockDim.x + threadIdx.x) >> 6;
  const int l = threadIdx.x & 63;
  int n = *cnt; if (n > CAND_CAP) n = CAND_CAP;
  for (int ci = wid; ci < n; ci += nw) {
    int4 cd = cand[ci];
    float maxA = unfkey(packedA[cd.x]);
    float apx = __int_as_float(cd.z);
    if (apx < maxA - MARGIN) continue;     // provably not the winner
    const float4* qp = (const float4*)(Q + (size_t)cd.x * DIM);
    const float4* sp = (const float4*)(S + (size_t)cd.y * DIM);
    float4 a0 = qp[l], b0 = sp[l], a1 = qp[l + 64], b1 = sp[l + 64];
    float d = a0.x*b0.x + a0.y*b0.y + a0.z*b0.z + a0.w*b0.w
            + a1.x*b1.x + a1.y*b1.y + a1.z*b1.z + a1.w*b1.w;
    #pragma unroll
    for (int off = 32; off; off >>= 1) d += __shfl_xor(d, off);
    if (l == 0) {
      float ex = d * rq[cd.x] * rs[cd.y];
      unsigned long long p =
          ((unsigned long long)fkey(ex) << 32) | (uint32_t)(~(uint32_t)cd.y);
      atomicMax(&packedE[cd.x], p);
    }
  }
}

__global__ void finalize_kernel(const unsigned long long* __restrict__ packedE,
                                const int* __restrict__ lab, float* __restrict__ out) {
  int gid = blockIdx.x * 256 + threadIdx.x;
  if (gid >= NQ * NC) return;
  int q = gid >> 6, cl = gid & 63;
  unsigned long long p = packedE[q];
  if (p == 0ull) { out[gid] = 0.0f; return; }   // safety: never expected
  uint32_t n = ~(uint32_t)p;
  float v = unfkey((uint32_t)(p >> 32));
  out[gid] = (cl == lab[n]) ? v : 0.0f;
}

// ---------- launch ----------
extern "C" void kernel_launch(void* const* d_in, const int* in_sizes, int n_in,
                              void* d_out, int out_size, void* d_ws, size_t ws_size,
                              hipStream_t stream) {
  const float* Q  = (const float*)d_in[0];   // [8192, 512]
  const float* S  = (const float*)d_in[1];   // [16384, 512]
  const float* OH = (const float*)d_in[2];   // [16384, 64]
  float* out = (float*)d_out;                // [8192, 64]

  char* ws = (char*)d_ws;
  int* lab                    = (int*)(ws);                             //  64 KB
  unsigned long long* packedE = (unsigned long long*)(ws + (1 << 16));  //  64 KB
  uint32_t* packedA           = (uint32_t*)(ws + (2 << 16));            //  32 KB
  int* cnt                    = (int*)(ws + (3 << 16));                 //   4 KB
  float* rq                   = (float*)(ws + 200704);                  //  32 KB
  float* rs                   = (float*)(ws + 233472);                  //  64 KB
  ushort* Qbf                 = (ushort*)(ws + 299008);                 //   8 MB
  ushort* Sbf                 = (ushort*)(ws + 299008 + 8388608);       //  16 MB
  int4* cand                  = (int4*)(ws + 299008 + 8388608 + 16777216); // 16 MB

  norm_bf16_kernel<<<NQ / 4, 256, 0, stream>>>(Q, Qbf, rq, NQ);
  norm_bf16_kernel<<<NS / 4, 256, 0, stream>>>(S, Sbf, rs, NS);
  label_init_kernel<<<NS / 256, 256, 0, stream>>>(OH, lab, packedE, packedA, cnt);

  gemm_margin_kernel<<<(NQ / BM) * SSPLIT, 512, 0, stream>>>(Qbf, Sbf, packedA, cand, cnt);

  rescore_kernel<<<2048, 256, 0, stream>>>(Q, S, rq, rs, packedA, cand, cnt, packedE);

  finalize_kernel<<<(NQ * NC) / 256, 256, 0, stream>>>(packedE, lab, out);
}